// Round 9
// baseline (710.819 us; speedup 1.0000x reference)
//
#include <hip/hip_runtime.h>

using u32 = unsigned int;
using u16 = unsigned short;

typedef __attribute__((ext_vector_type(8)))  __bf16 bf16x8;
typedef __attribute__((ext_vector_type(16))) float  f32x16;
typedef __attribute__((ext_vector_type(4)))  float  f32x4;
typedef __attribute__((ext_vector_type(4)))  int    i32x4;

__device__ __forceinline__ u32 f2bf(float f){
  u32 u = __float_as_uint(f);
  return (u + 0x7FFFu + ((u >> 16) & 1u)) >> 16;
}
__device__ __forceinline__ u32 pack2bf(float lo, float hi){
  return f2bf(lo) | (f2bf(hi) << 16);
}
__device__ __forceinline__ float bfu2f(u32 us){ return __uint_as_float(us << 16); }
__device__ __forceinline__ float lrelu(float x){ return x > 0.f ? x : 0.01f * x; }

// ---------- K0: weight [512][256] f32 -> wT [256][512] bf16 ----------
__global__ void k0_wt(const float* __restrict__ w, u16* __restrict__ wT){
  int u = blockIdx.x * 256 + threadIdx.x;
  int k = u >> 8, n = u & 255;
  wT[(size_t)n * 512 + k] = (u16)f2bf(w[(size_t)k * 256 + n]);
}

// ---------- K1: out = x@W -> outF (MFMA-frag layout) + v0/v1 + p(bf16) ----------
__global__ __launch_bounds__(512, 2) void k1_gemm(const float* __restrict__ x,
    const u16* __restrict__ wT, const float* __restrict__ av, u16* __restrict__ outF,
    float* __restrict__ v0, float* __restrict__ v1, u16* __restrict__ pbf){
  __shared__ float tb[8][32][36];
  __shared__ float afl[512];
  __shared__ float sred[2][32][17];
  __shared__ float srw[2][32];
  const int i0 = blockIdx.x * 32;
  const int tid = threadIdx.x;
  const int lane = tid & 63, wv = tid >> 6;
  const int r = lane & 31, h = lane >> 5;
  const float* xp = x + (size_t)(i0 + r) * 512 + h * 8;
  const u16*   bp = wT + (size_t)(wv * 32 + r) * 512 + h * 8;
  f32x16 acc = {};
  for (int s = 0; s < 32; ++s){
    f32x4 a0 = *(const f32x4*)xp;
    f32x4 a1 = *(const f32x4*)(xp + 4);
    i32x4 pk = { (int)pack2bf(a0[0], a0[1]), (int)pack2bf(a0[2], a0[3]),
                 (int)pack2bf(a1[0], a1[1]), (int)pack2bf(a1[2], a1[3]) };
    bf16x8 af = __builtin_bit_cast(bf16x8, pk);
    bf16x8 bf = *(const bf16x8*)bp;
    acc = __builtin_amdgcn_mfma_f32_32x32x16_bf16(af, bf, acc, 0, 0, 0);
    xp += 16; bp += 16;
  }
  #pragma unroll
  for (int re = 0; re < 16; ++re){
    int rr = (re & 3) + 8 * (re >> 2) + 4 * h;
    tb[wv][r][rr] = acc[re];
  }
  afl[tid] = av[tid];
  __syncthreads();
  {
    const int n2 = lane >> 1, ic = (lane & 1) * 16;
    const float* tp = &tb[wv][n2][ic];
    i32x4 w0 = { (int)pack2bf(tp[0],tp[1]),   (int)pack2bf(tp[2],tp[3]),
                 (int)pack2bf(tp[4],tp[5]),   (int)pack2bf(tp[6],tp[7]) };
    i32x4 w1 = { (int)pack2bf(tp[8],tp[9]),   (int)pack2bf(tp[10],tp[11]),
                 (int)pack2bf(tp[12],tp[13]), (int)pack2bf(tp[14],tp[15]) };
    const int n = wv * 32 + n2;
    const int k16 = (i0 + ic) >> 4;
    u16* op = outF + ((size_t)k16 * 256 + n) * 16;
    *(i32x4*)op = w0;
    *((i32x4*)op + 1) = w1;
  }
  const int row = tid & 31, g = tid >> 5;
  const int w8 = g >> 1, fh = (g & 1) * 16;
  float a1c = 0.f, a2c = 0.f;
  #pragma unroll
  for (int f = 0; f < 16; ++f){
    float tv = tb[w8][fh + f][row];
    a1c = fmaf(tv, afl[w8 * 32 + fh + f], a1c);
    a2c = fmaf(tv, afl[256 + w8 * 32 + fh + f], a2c);
  }
  sred[0][row][g] = a1c; sred[1][row][g] = a2c;
  __syncthreads();
  if (tid < 64){
    int which = tid >> 5, r2 = tid & 31;
    float s = 0.f;
    #pragma unroll
    for (int g2 = 0; g2 < 16; ++g2) s += sred[which][r2][g2];
    srw[which][r2] = s;
  }
  __syncthreads();
  if (tid < 16){
    int k = (i0 >> 1) + tid;
    float sa  = srw[0][2*tid],   sb  = srw[1][2*tid];
    float sa1 = srw[0][2*tid+1], sb1 = srw[1][2*tid+1];
    v0[k] = lrelu(sa + sb);
    v1[k] = lrelu(sa1 + sb1);
    float w = lrelu(sa + sb1);
    pbf[k] = (u16)f2bf(__expf(w));
  }
}

// ---------- K3: binary GEMM, 4-wave blocks (W=4 LDS sharing), 128-K phases ----------
// grid 512 (2/CU): xcd=bid&7 -> chunk c=xcd>>1, row-half=xcd&1; slot=bid>>3.
// Block: 64 rows x 256 feats x K-chunk 2048. 4 waves, each 64r x 64f (acc 4x f32x16).
// 16 phases of 128 K; each phase = 2 subs of 64 K. B double-buffered per sub (regs),
// A staged to LDS (XOR-swizzled), adj issued a full phase early. 1 barrier/phase.
__global__ void k3_main(const int* __restrict__ adj,
    const u16* __restrict__ outF, const u16* __restrict__ pbf,
    float* __restrict__ P, float* __restrict__ pd){
  __shared__ u16 Ab[2][2][4096];   // [buf][sub][cc(8)][slot=row^cc(64)][8] bf16
  __shared__ u32 pl32[1024];       // p bf16-pairs for this chunk
  __shared__ float dred[64][5];
  const int bid = blockIdx.x;
  const int xcd = bid & 7, slot = bid >> 3;
  const int c = xcd >> 1;
  const int tile = (xcd & 1) * 64 + slot;     // 0..127 ; <64 top, >=64 bottom
  const bool top = tile < 64;
  const int i0 = tile * 64;
  const int kbase = c * 2048;
  const int pb = tile * 4 + c;
  const int tid = threadIdx.x, lane = tid & 63, wv = tid >> 6;
  const int r = lane & 31, h = lane >> 5;
  const int fb = wv * 64;
  const int srow = tid >> 2, sseg = tid & 3;
  const int sub_ = sseg >> 1, s2 = sseg & 1;
  const int h8 = h * 8;
  const int* aq0 = adj + (size_t)(i0 + srow) * 8192 + kbase + sseg * 32;
  const u16* bq0 = outF + ((size_t)(kbase >> 4) * 256 + fb + r) * 16 + h8;
  u16* const wbase = &Ab[0][0][0] + sub_ * 4096;   // + buf*8192, cc*512, slot*8
  const u32* const pq0 = pl32 + sseg * 16;          // + t*64, q*4

  // stage p-pairs (chunk slice; p has period 4096 -> chunk c uses half (c&1))
  if (top){
    pl32[tid] = 0x3F803F80u; pl32[tid + 256] = 0x3F803F80u;
    pl32[tid + 512] = 0x3F803F80u; pl32[tid + 768] = 0x3F803F80u;
  } else {
    const u32* ps = (const u32*)pbf + (c & 1) * 1024;
    pl32[tid] = ps[tid]; pl32[tid + 256] = ps[tid + 256];
    pl32[tid + 512] = ps[tid + 512]; pl32[tid + 768] = ps[tid + 768];
  }
  __syncthreads();

  i32x4 ar[8];
  bf16x8 BA[8], BB[8];
  f32x16 a00 = {}, a01 = {}, a10 = {}, a11 = {};
  float d = 0.f;

#define ADJ_ISS(T_) { const int* ap_ = aq0 + (T_) * 128; \
  _Pragma("unroll") for (int q = 0; q < 8; ++q) \
    ar[q] = __builtin_nontemporal_load((const i32x4*)(ap_ + q * 4)); \
  asm volatile("" ::: "memory"); }

#define B_ISS(B_,U_) { const u16* bb_ = bq0 + (size_t)(U_) * 16384; \
  _Pragma("unroll") for (int ks = 0; ks < 4; ++ks){ \
    B_[ks*2]   = *(const bf16x8*)(bb_ + ks * 4096); \
    B_[ks*2+1] = *(const bf16x8*)(bb_ + ks * 4096 + 512); } \
  asm volatile("" ::: "memory"); }

#define MFMA_SUB(B_,BUF_,SUB_) { \
  const u16* rb_ = &Ab[0][0][0] + (BUF_) * 8192 + (SUB_) * 4096; \
  __builtin_amdgcn_s_setprio(1); \
  _Pragma("unroll") for (int ks = 0; ks < 4; ++ks){ \
    const int cc_ = ks * 2 + h; \
    bf16x8 af0_ = *(const bf16x8*)(rb_ + cc_ * 512 + ((r ^ cc_) * 8)); \
    bf16x8 af1_ = *(const bf16x8*)(rb_ + cc_ * 512 + (((32 + r) ^ cc_) * 8)); \
    a00 = __builtin_amdgcn_mfma_f32_32x32x16_bf16(af0_, B_[ks*2],   a00, 0, 0, 0); \
    a01 = __builtin_amdgcn_mfma_f32_32x32x16_bf16(af0_, B_[ks*2+1], a01, 0, 0, 0); \
    a10 = __builtin_amdgcn_mfma_f32_32x32x16_bf16(af1_, B_[ks*2],   a10, 0, 0, 0); \
    a11 = __builtin_amdgcn_mfma_f32_32x32x16_bf16(af1_, B_[ks*2+1], a11, 0, 0, 0); } \
  __builtin_amdgcn_s_setprio(0); }

#define PACKW(T_,BUF_) { \
  u16* wb_ = wbase + (BUF_) * 8192 + ((/*cc base*/ s2 * 4) * 512); \
  _Pragma("unroll") for (int q = 0; q < 4; ++q){ \
    i32x4 pv_ = *(const i32x4*)(pq0 + (T_) * 64 + q * 4); \
    i32x4 alo_ = ar[2*q], ahi_ = ar[2*q+1]; \
    u32 w0_ = ((((u32)(-alo_[0])) & 0xFFFFu) | (((u32)(-alo_[1])) << 16)) & (u32)pv_[0]; \
    u32 w1_ = ((((u32)(-alo_[2])) & 0xFFFFu) | (((u32)(-alo_[3])) << 16)) & (u32)pv_[1]; \
    u32 w2_ = ((((u32)(-ahi_[0])) & 0xFFFFu) | (((u32)(-ahi_[1])) << 16)) & (u32)pv_[2]; \
    u32 w3_ = ((((u32)(-ahi_[2])) & 0xFFFFu) | (((u32)(-ahi_[3])) << 16)) & (u32)pv_[3]; \
    d += __uint_as_float(w0_ << 16) + __uint_as_float(w0_ & 0xFFFF0000u); \
    d += __uint_as_float(w1_ << 16) + __uint_as_float(w1_ & 0xFFFF0000u); \
    d += __uint_as_float(w2_ << 16) + __uint_as_float(w2_ & 0xFFFF0000u); \
    d += __uint_as_float(w3_ << 16) + __uint_as_float(w3_ & 0xFFFF0000u); \
    i32x4 wv_ = { (int)w0_, (int)w1_, (int)w2_, (int)w3_ }; \
    const int cc_ = s2 * 4 + q; \
    *(i32x4*)(wb_ + q * 512 + (((srow ^ cc_) * 8))) = wv_; } }

#define KBAR() { asm volatile("s_waitcnt lgkmcnt(0)" ::: "memory"); \
  __builtin_amdgcn_s_barrier(); asm volatile("" ::: "memory"); }

  // prologue
  ADJ_ISS(0);
  B_ISS(BA, 0);
  PACKW(0, 0);
  KBAR();
  #pragma unroll 1
  for (int t = 0; t < 15; ++t){
    B_ISS(BB, 2 * t + 1);
    ADJ_ISS(t + 1);
    MFMA_SUB(BA, t & 1, 0);
    B_ISS(BA, 2 * t + 2);
    MFMA_SUB(BB, t & 1, 1);
    PACKW(t + 1, (t + 1) & 1);
    KBAR();
  }
  // tail phase t=15 (buf 1)
  B_ISS(BB, 31);
  MFMA_SUB(BA, 1, 0);
  MFMA_SUB(BB, 1, 1);

#undef ADJ_ISS
#undef B_ISS
#undef MFMA_SUB
#undef PACKW
#undef KBAR

  // ---- epilogue: denominator reduce + partial store ----
  dred[srow][sseg] = d;
  __syncthreads();
  if (tid < 64){
    float s = dred[tid][0] + dred[tid][1] + dred[tid][2] + dred[tid][3];
    pd[(size_t)pb * 64 + tid] = s;
  }
  float* Pb = P + (size_t)pb * 16384 + fb + r;
  #pragma unroll
  for (int e = 0; e < 16; ++e){
    int rr = (e & 3) + 8 * (e >> 2) + 4 * h;
    __builtin_nontemporal_store(a00[e], Pb + (size_t)rr * 256);
    __builtin_nontemporal_store(a01[e], Pb + (size_t)rr * 256 + 32);
    __builtin_nontemporal_store(a10[e], Pb + (size_t)(rr + 32) * 256);
    __builtin_nontemporal_store(a11[e], Pb + (size_t)(rr + 32) * 256 + 32);
  }
}

// ---------- K4: combine 4 K-split partials + softmax coeffs + sigmoid ----------
__global__ void k4_final(const float* __restrict__ P, const float* __restrict__ pd,
    const float* __restrict__ v0, const float* __restrict__ v1, float* __restrict__ out){
  const int i = blockIdx.x, n = threadIdx.x;
  const int tile = i >> 6, rloc = i & 63;
  const size_t base = ((size_t)tile * 4 * 64 + rloc) * 256 + n;
  float P0 = __builtin_nontemporal_load(P + base);
  float P1 = __builtin_nontemporal_load(P + base + 16384);
  float P2 = __builtin_nontemporal_load(P + base + 32768);
  float P3 = __builtin_nontemporal_load(P + base + 49152);
  const float* pdp = pd + (size_t)tile * 256 + rloc;
  float d0 = pdp[0], d1 = pdp[64], d2 = pdp[128], d3 = pdp[192];
  float val;
  if (i < 4096){
    float va = v0[i], vb = v1[i];
    float m = fmaxf(va, vb);
    float e0 = __expf(va - m), e1 = __expf(vb - m);
    val = (e0 * (P0 + P1) + e1 * (P2 + P3)) / (e0 * (d0 + d1) + e1 * (d2 + d3));
  } else {
    val = (P0 + P1 + P2 + P3) / (d0 + d1 + d2 + d3);
  }
  out[(size_t)i * 256 + n] = 1.0f / (1.0f + __expf(-val));
}

extern "C" void kernel_launch(void* const* d_in, const int* in_sizes, int n_in,
                              void* d_out, int out_size, void* d_ws, size_t ws_size,
                              hipStream_t stream)
{
  const float* x      = (const float*)d_in[0];
  const float* weight = (const float*)d_in[1];
  const float* av     = (const float*)d_in[2];
  const int*   adj    = (const int*)d_in[3];
  float* out = (float*)d_out;
  char* ws = (char*)d_ws;
  float* P     = (float*)(ws + 0);             // 33,554,432 B
  float* pd    = (float*)(ws + 33554432);      //    131,072 B
  u16*   outF  = (u16*)  (ws + 33685504);      //  4,194,304 B
  u16*   wT    = (u16*)  (ws + 37879808);      //    262,144 B
  u16*   pbf   = (u16*)  (ws + 38141952);      //      8,192 B
  float* v0    = (float*)(ws + 38150144);      //     16,384 B
  float* v1    = (float*)(ws + 38166528);      //     16,384 B

  k0_wt    <<<512, 256, 0, stream>>>(weight, wT);
  k1_gemm  <<<256, 512, 0, stream>>>(x, wT, av, outF, v0, v1, pbf);
  k3_main  <<<512, 256, 0, stream>>>(adj, outF, pbf, P, pd);
  k4_final <<<8192, 256, 0, stream>>>(P, pd, v0, v1, out);
}

// Round 10
// 195.292 us; speedup vs baseline: 3.6398x; 3.6398x over previous
//
#include <hip/hip_runtime.h>

using u32 = unsigned int;
using u16 = unsigned short;

typedef __attribute__((ext_vector_type(8)))  __bf16 bf16x8;
typedef __attribute__((ext_vector_type(16))) float  f32x16;
typedef __attribute__((ext_vector_type(4)))  float  f32x4;
typedef __attribute__((ext_vector_type(4)))  int    i32x4;

__device__ __forceinline__ u32 f2bf(float f){
  u32 u = __float_as_uint(f);
  return (u + 0x7FFFu + ((u >> 16) & 1u)) >> 16;
}
__device__ __forceinline__ u32 pack2bf(float lo, float hi){
  return f2bf(lo) | (f2bf(hi) << 16);
}
__device__ __forceinline__ float bfu2f(u32 us){ return __uint_as_float(us << 16); }
__device__ __forceinline__ float lrelu(float x){ return x > 0.f ? x : 0.01f * x; }

// ---------- K0: weight [512][256] f32 -> wT [256][512] bf16 ----------
__global__ void k0_wt(const float* __restrict__ w, u16* __restrict__ wT){
  int u = blockIdx.x * 256 + threadIdx.x;
  int k = u >> 8, n = u & 255;
  wT[(size_t)n * 512 + k] = (u16)f2bf(w[(size_t)k * 256 + n]);
}

// ---------- K1: out = x@W -> outF (MFMA-frag layout) + v0/v1 + p(bf16) ----------
__global__ __launch_bounds__(512, 2) void k1_gemm(const float* __restrict__ x,
    const u16* __restrict__ wT, const float* __restrict__ av, u16* __restrict__ outF,
    float* __restrict__ v0, float* __restrict__ v1, u16* __restrict__ pbf){
  __shared__ float tb[8][32][36];
  __shared__ float afl[512];
  __shared__ float sred[2][32][17];
  __shared__ float srw[2][32];
  const int i0 = blockIdx.x * 32;
  const int tid = threadIdx.x;
  const int lane = tid & 63, wv = tid >> 6;
  const int r = lane & 31, h = lane >> 5;
  const float* xp = x + (size_t)(i0 + r) * 512 + h * 8;
  const u16*   bp = wT + (size_t)(wv * 32 + r) * 512 + h * 8;
  f32x16 acc = {};
  for (int s = 0; s < 32; ++s){
    f32x4 a0 = *(const f32x4*)xp;
    f32x4 a1 = *(const f32x4*)(xp + 4);
    i32x4 pk = { (int)pack2bf(a0[0], a0[1]), (int)pack2bf(a0[2], a0[3]),
                 (int)pack2bf(a1[0], a1[1]), (int)pack2bf(a1[2], a1[3]) };
    bf16x8 af = __builtin_bit_cast(bf16x8, pk);
    bf16x8 bf = *(const bf16x8*)bp;
    acc = __builtin_amdgcn_mfma_f32_32x32x16_bf16(af, bf, acc, 0, 0, 0);
    xp += 16; bp += 16;
  }
  #pragma unroll
  for (int re = 0; re < 16; ++re){
    int rr = (re & 3) + 8 * (re >> 2) + 4 * h;
    tb[wv][r][rr] = acc[re];
  }
  afl[tid] = av[tid];
  __syncthreads();
  {
    const int n2 = lane >> 1, ic = (lane & 1) * 16;
    const float* tp = &tb[wv][n2][ic];
    i32x4 w0 = { (int)pack2bf(tp[0],tp[1]),   (int)pack2bf(tp[2],tp[3]),
                 (int)pack2bf(tp[4],tp[5]),   (int)pack2bf(tp[6],tp[7]) };
    i32x4 w1 = { (int)pack2bf(tp[8],tp[9]),   (int)pack2bf(tp[10],tp[11]),
                 (int)pack2bf(tp[12],tp[13]), (int)pack2bf(tp[14],tp[15]) };
    const int n = wv * 32 + n2;
    const int k16 = (i0 + ic) >> 4;
    u16* op = outF + ((size_t)k16 * 256 + n) * 16;
    *(i32x4*)op = w0;
    *((i32x4*)op + 1) = w1;
  }
  const int row = tid & 31, g = tid >> 5;
  const int w8 = g >> 1, fh = (g & 1) * 16;
  float a1c = 0.f, a2c = 0.f;
  #pragma unroll
  for (int f = 0; f < 16; ++f){
    float tv = tb[w8][fh + f][row];
    a1c = fmaf(tv, afl[w8 * 32 + fh + f], a1c);
    a2c = fmaf(tv, afl[256 + w8 * 32 + fh + f], a2c);
  }
  sred[0][row][g] = a1c; sred[1][row][g] = a2c;
  __syncthreads();
  if (tid < 64){
    int which = tid >> 5, r2 = tid & 31;
    float s = 0.f;
    #pragma unroll
    for (int g2 = 0; g2 < 16; ++g2) s += sred[which][r2][g2];
    srw[which][r2] = s;
  }
  __syncthreads();
  if (tid < 16){
    int k = (i0 >> 1) + tid;
    float sa  = srw[0][2*tid],   sb  = srw[1][2*tid];
    float sa1 = srw[0][2*tid+1], sb1 = srw[1][2*tid+1];
    v0[k] = lrelu(sa + sb);
    v1[k] = lrelu(sa1 + sb1);
    float w = lrelu(sa + sb1);
    pbf[k] = (u16)f2bf(__expf(w));
  }
}

// ---------- K3: binary GEMM, 4-wave blocks (W=4 LDS sharing), 128-K phases ----------
// grid 512 (2/CU): xcd=bid&7 -> chunk c=xcd>>1, row-half=xcd&1; slot=bid>>3.
// Block: 64 rows x 256 feats x K-chunk 2048. 4 waves, each 64r x 64f (acc 4x f32x16).
// 16 phases of 128 K; each phase = 2 subs of 64 K. B double-buffered per sub (regs),
// A staged to LDS (XOR-swizzled), adj issued a full phase early. 1 barrier/phase.
// __launch_bounds__(256,2): VGPR cap 256 (R9 default-bounds spill trap: cap 64).
__global__ __launch_bounds__(256, 2) void k3_main(const int* __restrict__ adj,
    const u16* __restrict__ outF, const u16* __restrict__ pbf,
    float* __restrict__ P, float* __restrict__ pd){
  __shared__ u16 Ab[2][2][4096];   // [buf][sub][cc(8)][slot=row^cc(64)][8] bf16
  __shared__ u32 pl32[1024];       // p bf16-pairs for this chunk
  __shared__ float dred[64][5];
  const int bid = blockIdx.x;
  const int xcd = bid & 7, slot = bid >> 3;
  const int c = xcd >> 1;
  const int tile = (xcd & 1) * 64 + slot;     // 0..127 ; <64 top, >=64 bottom
  const bool top = tile < 64;
  const int i0 = tile * 64;
  const int kbase = c * 2048;
  const int pb = tile * 4 + c;
  const int tid = threadIdx.x, lane = tid & 63, wv = tid >> 6;
  const int r = lane & 31, h = lane >> 5;
  const int fb = wv * 64;
  const int srow = tid >> 2, sseg = tid & 3;
  const int sub_ = sseg >> 1, s2 = sseg & 1;
  const int h8 = h * 8;
  const int* aq0 = adj + (size_t)(i0 + srow) * 8192 + kbase + sseg * 32;
  const u16* bq0 = outF + ((size_t)(kbase >> 4) * 256 + fb + r) * 16 + h8;
  u16* const wbase = &Ab[0][0][0] + sub_ * 4096;   // + buf*8192, cc*512, slot*8
  const u32* const pq0 = pl32 + sseg * 16;          // + t*64, q*4

  // stage p-pairs (chunk slice; p has period 4096 -> chunk c uses half (c&1))
  if (top){
    pl32[tid] = 0x3F803F80u; pl32[tid + 256] = 0x3F803F80u;
    pl32[tid + 512] = 0x3F803F80u; pl32[tid + 768] = 0x3F803F80u;
  } else {
    const u32* ps = (const u32*)pbf + (c & 1) * 1024;
    pl32[tid] = ps[tid]; pl32[tid + 256] = ps[tid + 256];
    pl32[tid + 512] = ps[tid + 512]; pl32[tid + 768] = ps[tid + 768];
  }
  __syncthreads();

  i32x4 ar[8];
  bf16x8 BA[8], BB[8];
  f32x16 a00 = {}, a01 = {}, a10 = {}, a11 = {};
  float d = 0.f;

#define ADJ_ISS(T_) { const int* ap_ = aq0 + (T_) * 128; \
  _Pragma("unroll") for (int q = 0; q < 8; ++q) \
    ar[q] = __builtin_nontemporal_load((const i32x4*)(ap_ + q * 4)); \
  asm volatile("" ::: "memory"); }

#define B_ISS(B_,U_) { const u16* bb_ = bq0 + (size_t)(U_) * 16384; \
  _Pragma("unroll") for (int ks = 0; ks < 4; ++ks){ \
    B_[ks*2]   = *(const bf16x8*)(bb_ + ks * 4096); \
    B_[ks*2+1] = *(const bf16x8*)(bb_ + ks * 4096 + 512); } \
  asm volatile("" ::: "memory"); }

#define MFMA_SUB(B_,BUF_,SUB_) { \
  const u16* rb_ = &Ab[0][0][0] + (BUF_) * 8192 + (SUB_) * 4096; \
  __builtin_amdgcn_s_setprio(1); \
  _Pragma("unroll") for (int ks = 0; ks < 4; ++ks){ \
    const int cc_ = ks * 2 + h; \
    bf16x8 af0_ = *(const bf16x8*)(rb_ + cc_ * 512 + ((r ^ cc_) * 8)); \
    bf16x8 af1_ = *(const bf16x8*)(rb_ + cc_ * 512 + (((32 + r) ^ cc_) * 8)); \
    a00 = __builtin_amdgcn_mfma_f32_32x32x16_bf16(af0_, B_[ks*2],   a00, 0, 0, 0); \
    a01 = __builtin_amdgcn_mfma_f32_32x32x16_bf16(af0_, B_[ks*2+1], a01, 0, 0, 0); \
    a10 = __builtin_amdgcn_mfma_f32_32x32x16_bf16(af1_, B_[ks*2],   a10, 0, 0, 0); \
    a11 = __builtin_amdgcn_mfma_f32_32x32x16_bf16(af1_, B_[ks*2+1], a11, 0, 0, 0); } \
  __builtin_amdgcn_s_setprio(0); }

#define PACKW(T_,BUF_) { \
  u16* wb_ = wbase + (BUF_) * 8192 + ((s2 * 4) * 512); \
  _Pragma("unroll") for (int q = 0; q < 4; ++q){ \
    i32x4 pv_ = *(const i32x4*)(pq0 + (T_) * 64 + q * 4); \
    i32x4 alo_ = ar[2*q], ahi_ = ar[2*q+1]; \
    u32 w0_ = ((((u32)(-alo_[0])) & 0xFFFFu) | (((u32)(-alo_[1])) << 16)) & (u32)pv_[0]; \
    u32 w1_ = ((((u32)(-alo_[2])) & 0xFFFFu) | (((u32)(-alo_[3])) << 16)) & (u32)pv_[1]; \
    u32 w2_ = ((((u32)(-ahi_[0])) & 0xFFFFu) | (((u32)(-ahi_[1])) << 16)) & (u32)pv_[2]; \
    u32 w3_ = ((((u32)(-ahi_[2])) & 0xFFFFu) | (((u32)(-ahi_[3])) << 16)) & (u32)pv_[3]; \
    d += __uint_as_float(w0_ << 16) + __uint_as_float(w0_ & 0xFFFF0000u); \
    d += __uint_as_float(w1_ << 16) + __uint_as_float(w1_ & 0xFFFF0000u); \
    d += __uint_as_float(w2_ << 16) + __uint_as_float(w2_ & 0xFFFF0000u); \
    d += __uint_as_float(w3_ << 16) + __uint_as_float(w3_ & 0xFFFF0000u); \
    i32x4 wv_ = { (int)w0_, (int)w1_, (int)w2_, (int)w3_ }; \
    const int cc_ = s2 * 4 + q; \
    *(i32x4*)(wb_ + q * 512 + (((srow ^ cc_) * 8))) = wv_; } }

#define KBAR() { asm volatile("s_waitcnt lgkmcnt(0)" ::: "memory"); \
  __builtin_amdgcn_s_barrier(); asm volatile("" ::: "memory"); }

  // prologue
  ADJ_ISS(0);
  B_ISS(BA, 0);
  PACKW(0, 0);
  KBAR();
  #pragma unroll 1
  for (int t = 0; t < 15; ++t){
    B_ISS(BB, 2 * t + 1);
    ADJ_ISS(t + 1);
    MFMA_SUB(BA, t & 1, 0);
    B_ISS(BA, 2 * t + 2);
    MFMA_SUB(BB, t & 1, 1);
    PACKW(t + 1, (t + 1) & 1);
    KBAR();
  }
  // tail phase t=15 (buf 1)
  B_ISS(BB, 31);
  MFMA_SUB(BA, 1, 0);
  MFMA_SUB(BB, 1, 1);

#undef ADJ_ISS
#undef B_ISS
#undef MFMA_SUB
#undef PACKW
#undef KBAR

  // ---- epilogue: denominator reduce + partial store ----
  dred[srow][sseg] = d;
  __syncthreads();
  if (tid < 64){
    float s = dred[tid][0] + dred[tid][1] + dred[tid][2] + dred[tid][3];
    pd[(size_t)pb * 64 + tid] = s;
  }
  float* Pb = P + (size_t)pb * 16384 + fb + r;
  #pragma unroll
  for (int e = 0; e < 16; ++e){
    int rr = (e & 3) + 8 * (e >> 2) + 4 * h;
    __builtin_nontemporal_store(a00[e], Pb + (size_t)rr * 256);
    __builtin_nontemporal_store(a01[e], Pb + (size_t)rr * 256 + 32);
    __builtin_nontemporal_store(a10[e], Pb + (size_t)(rr + 32) * 256);
    __builtin_nontemporal_store(a11[e], Pb + (size_t)(rr + 32) * 256 + 32);
  }
}

// ---------- K4: combine 4 K-split partials + softmax coeffs + sigmoid ----------
__global__ void k4_final(const float* __restrict__ P, const float* __restrict__ pd,
    const float* __restrict__ v0, const float* __restrict__ v1, float* __restrict__ out){
  const int i = blockIdx.x, n = threadIdx.x;
  const int tile = i >> 6, rloc = i & 63;
  const size_t base = ((size_t)tile * 4 * 64 + rloc) * 256 + n;
  float P0 = __builtin_nontemporal_load(P + base);
  float P1 = __builtin_nontemporal_load(P + base + 16384);
  float P2 = __builtin_nontemporal_load(P + base + 32768);
  float P3 = __builtin_nontemporal_load(P + base + 49152);
  const float* pdp = pd + (size_t)tile * 256 + rloc;
  float d0 = pdp[0], d1 = pdp[64], d2 = pdp[128], d3 = pdp[192];
  float val;
  if (i < 4096){
    float va = v0[i], vb = v1[i];
    float m = fmaxf(va, vb);
    float e0 = __expf(va - m), e1 = __expf(vb - m);
    val = (e0 * (P0 + P1) + e1 * (P2 + P3)) / (e0 * (d0 + d1) + e1 * (d2 + d3));
  } else {
    val = (P0 + P1 + P2 + P3) / (d0 + d1 + d2 + d3);
  }
  out[(size_t)i * 256 + n] = 1.0f / (1.0f + __expf(-val));
}

extern "C" void kernel_launch(void* const* d_in, const int* in_sizes, int n_in,
                              void* d_out, int out_size, void* d_ws, size_t ws_size,
                              hipStream_t stream)
{
  const float* x      = (const float*)d_in[0];
  const float* weight = (const float*)d_in[1];
  const float* av     = (const float*)d_in[2];
  const int*   adj    = (const int*)d_in[3];
  float* out = (float*)d_out;
  char* ws = (char*)d_ws;
  float* P     = (float*)(ws + 0);             // 33,554,432 B
  float* pd    = (float*)(ws + 33554432);      //    131,072 B
  u16*   outF  = (u16*)  (ws + 33685504);      //  4,194,304 B
  u16*   wT    = (u16*)  (ws + 37879808);      //    262,144 B
  u16*   pbf   = (u16*)  (ws + 38141952);      //      8,192 B
  float* v0    = (float*)(ws + 38150144);      //     16,384 B
  float* v1    = (float*)(ws + 38166528);      //     16,384 B

  k0_wt    <<<512, 256, 0, stream>>>(weight, wT);
  k1_gemm  <<<256, 512, 0, stream>>>(x, wT, av, outF, v0, v1, pbf);
  k3_main  <<<512, 256, 0, stream>>>(adj, outF, pbf, P, pd);
  k4_final <<<8192, 256, 0, stream>>>(P, pd, v0, v1, out);
}

// Round 11
// 116.829 us; speedup vs baseline: 6.0843x; 1.6716x over previous
//
#include <hip/hip_runtime.h>

using u32 = unsigned int;
using u16 = unsigned short;

typedef __attribute__((ext_vector_type(8)))  __bf16 bf16x8;
typedef __attribute__((ext_vector_type(16))) float  f32x16;
typedef __attribute__((ext_vector_type(4)))  float  f32x4;
typedef __attribute__((ext_vector_type(4)))  int    i32x4;

__device__ __forceinline__ u32 f2bf(float f){
  u32 u = __float_as_uint(f);
  return (u + 0x7FFFu + ((u >> 16) & 1u)) >> 16;
}
__device__ __forceinline__ u32 pack2bf(float lo, float hi){
  return f2bf(lo) | (f2bf(hi) << 16);
}
__device__ __forceinline__ float bfu2f(u32 us){ return __uint_as_float(us << 16); }
__device__ __forceinline__ float lrelu(float x){ return x > 0.f ? x : 0.01f * x; }

// ---------- K0: weight [512][256] f32 -> wT [256][512] bf16 ----------
__global__ void k0_wt(const float* __restrict__ w, u16* __restrict__ wT){
  int u = blockIdx.x * 256 + threadIdx.x;
  int k = u >> 8, n = u & 255;
  wT[(size_t)n * 512 + k] = (u16)f2bf(w[(size_t)k * 256 + n]);
}

// ---------- K1: out = x@W -> outF (MFMA-frag layout) + v0/v1 + p(bf16) ----------
__global__ __launch_bounds__(512, 2) void k1_gemm(const float* __restrict__ x,
    const u16* __restrict__ wT, const float* __restrict__ av, u16* __restrict__ outF,
    float* __restrict__ v0, float* __restrict__ v1, u16* __restrict__ pbf){
  __shared__ float tb[8][32][36];
  __shared__ float afl[512];
  __shared__ float sred[2][32][17];
  __shared__ float srw[2][32];
  const int i0 = blockIdx.x * 32;
  const int tid = threadIdx.x;
  const int lane = tid & 63, wv = tid >> 6;
  const int r = lane & 31, h = lane >> 5;
  const float* xp = x + (size_t)(i0 + r) * 512 + h * 8;
  const u16*   bp = wT + (size_t)(wv * 32 + r) * 512 + h * 8;
  f32x16 acc = {};
  for (int s = 0; s < 32; ++s){
    f32x4 a0 = *(const f32x4*)xp;
    f32x4 a1 = *(const f32x4*)(xp + 4);
    i32x4 pk = { (int)pack2bf(a0[0], a0[1]), (int)pack2bf(a0[2], a0[3]),
                 (int)pack2bf(a1[0], a1[1]), (int)pack2bf(a1[2], a1[3]) };
    bf16x8 af = __builtin_bit_cast(bf16x8, pk);
    bf16x8 bf = *(const bf16x8*)bp;
    acc = __builtin_amdgcn_mfma_f32_32x32x16_bf16(af, bf, acc, 0, 0, 0);
    xp += 16; bp += 16;
  }
  #pragma unroll
  for (int re = 0; re < 16; ++re){
    int rr = (re & 3) + 8 * (re >> 2) + 4 * h;
    tb[wv][r][rr] = acc[re];
  }
  afl[tid] = av[tid];
  __syncthreads();
  {
    const int n2 = lane >> 1, ic = (lane & 1) * 16;
    const float* tp = &tb[wv][n2][ic];
    i32x4 w0 = { (int)pack2bf(tp[0],tp[1]),   (int)pack2bf(tp[2],tp[3]),
                 (int)pack2bf(tp[4],tp[5]),   (int)pack2bf(tp[6],tp[7]) };
    i32x4 w1 = { (int)pack2bf(tp[8],tp[9]),   (int)pack2bf(tp[10],tp[11]),
                 (int)pack2bf(tp[12],tp[13]), (int)pack2bf(tp[14],tp[15]) };
    const int n = wv * 32 + n2;
    const int k16 = (i0 + ic) >> 4;
    u16* op = outF + ((size_t)k16 * 256 + n) * 16;
    *(i32x4*)op = w0;
    *((i32x4*)op + 1) = w1;
  }
  const int row = tid & 31, g = tid >> 5;
  const int w8 = g >> 1, fh = (g & 1) * 16;
  float a1c = 0.f, a2c = 0.f;
  #pragma unroll
  for (int f = 0; f < 16; ++f){
    float tv = tb[w8][fh + f][row];
    a1c = fmaf(tv, afl[w8 * 32 + fh + f], a1c);
    a2c = fmaf(tv, afl[256 + w8 * 32 + fh + f], a2c);
  }
  sred[0][row][g] = a1c; sred[1][row][g] = a2c;
  __syncthreads();
  if (tid < 64){
    int which = tid >> 5, r2 = tid & 31;
    float s = 0.f;
    #pragma unroll
    for (int g2 = 0; g2 < 16; ++g2) s += sred[which][r2][g2];
    srw[which][r2] = s;
  }
  __syncthreads();
  if (tid < 16){
    int k = (i0 >> 1) + tid;
    float sa  = srw[0][2*tid],   sb  = srw[1][2*tid];
    float sa1 = srw[0][2*tid+1], sb1 = srw[1][2*tid+1];
    v0[k] = lrelu(sa + sb);
    v1[k] = lrelu(sa1 + sb1);
    float w = lrelu(sa + sb1);
    pbf[k] = (u16)f2bf(__expf(w));
  }
}

// ---------- K3: binary GEMM, row-contiguous adj streaming, plain loads ----------
// grid 1024 (2/CU, 2 rounds): xcd=bid&7 -> chunk c=xcd>>1, row-half=xcd&1; slot=bid>>3.
// Block: 32 rows x 256 feats x K-chunk 2048 (16 phases of 128 K). 8 waves x 32 feats
// (acc = 1 f32x16). adj staged per PAIR of phases: each wave-instr reads 1 KB
// CONTIGUOUS from one adj row (64 lanes x 16B). ar[4] covers rows {w,8+w,16+w,24+w},
// cols lane*4 within the 256-col pair tile; lanes<32 pack phase h0, lanes>=32 h1.
// B ping-pong across phases (8 bf16x8 each). Issue order per phase: B first, adj last
// -> no consumer ever drains a younger HBM load. lgkmcnt-only barriers.
__global__ __launch_bounds__(512, 2) void k3_main(const int* __restrict__ adj,
    const u16* __restrict__ outF, const u16* __restrict__ pbf,
    float* __restrict__ P, float* __restrict__ pd){
  __shared__ u16 Ab[2][4096];      // [buf][ks(8)][row(32)][16 bf16] = 8KB each
  __shared__ u32 pl32[1024];       // p bf16-pairs for this chunk
  __shared__ float dred[32][66];
  const int bid = blockIdx.x;
  const int xcd = bid & 7, slot = bid >> 3;      // slot 0..127
  const int c = xcd >> 1;
  const int tile = (xcd & 1) * 128 + slot;       // 0..255 ; <128 top
  const bool top = tile < 128;
  const int i0 = tile * 32;
  const int kbase = c * 2048;
  const int pb = tile * 4 + c;
  const int tid = threadIdx.x, l = tid & 63, w = tid >> 6;
  const int r = l & 31, h = l >> 5;
  const int fb = w * 32;
  const int* aq0 = adj + (size_t)(i0 + w) * 8192 + kbase + l * 4;
  const u16* bq0 = outF + ((size_t)(kbase >> 4) * 256 + fb + r) * 16 + h * 8;

  // stage p-pairs (p has period 4096 -> chunk c uses half (c&1))
  if (top){
    pl32[tid] = 0x3F803F80u; pl32[tid + 512] = 0x3F803F80u;
  } else {
    const u32* ps = (const u32*)pbf + (c & 1) * 1024;
    pl32[tid] = ps[tid]; pl32[tid + 512] = ps[tid + 512];
  }
  __syncthreads();

  i32x4 ar[4];
  bf16x8 BA[8], BB[8];
  f32x16 acc = {};
  float d4[4] = {0.f, 0.f, 0.f, 0.f};

#define ADJ_ISS(PP_) { \
  _Pragma("unroll") for (int q = 0; q < 4; ++q) \
    ar[q] = *(const i32x4*)(aq0 + (size_t)q * 65536 + (PP_) * 256); \
  asm volatile("" ::: "memory"); }

#define B_ISS(B_,T_) { const u16* bb_ = bq0 + (size_t)(T_) * 32768; \
  _Pragma("unroll") for (int j = 0; j < 8; ++j) \
    B_[j] = *(const bf16x8*)(bb_ + j * 4096); \
  asm volatile("" ::: "memory"); }

#define MFMA8(B_,BUF_) { const u16* rb_ = &Ab[BUF_][0] + r * 16 + h * 8; \
  __builtin_amdgcn_s_setprio(1); \
  _Pragma("unroll") for (int j = 0; j < 8; ++j){ \
    bf16x8 a_ = *(const bf16x8*)(rb_ + j * 512); \
    acc = __builtin_amdgcn_mfma_f32_32x32x16_bf16(a_, B_[j], acc, 0, 0, 0); } \
  __builtin_amdgcn_s_setprio(0); }

// PACK half H_ (lanes with l>>5 == H_): write phase-slice into buf BUF_.
// thread's k-position within the 128-K phase: cl = (l&31)*4 -> ks = cl>>4.
#define PACKW(H_,BUF_,PP_) { \
  if ((l >> 5) == (H_)){ \
    const int ks_ = (l & 31) >> 2; \
    u32 pv0_ = pl32[(PP_) * 128 + l * 2]; \
    u32 pv1_ = pl32[(PP_) * 128 + l * 2 + 1]; \
    u16* wb_ = &Ab[BUF_][0] + ks_ * 512 + (l & 3) * 4; \
    _Pragma("unroll") for (int q = 0; q < 4; ++q){ \
      i32x4 a_ = ar[q]; \
      u32 w0_ = ((((u32)(-a_[0])) & 0xFFFFu) | (((u32)(-a_[1])) << 16)) & pv0_; \
      u32 w1_ = ((((u32)(-a_[2])) & 0xFFFFu) | (((u32)(-a_[3])) << 16)) & pv1_; \
      d4[q] += __uint_as_float(w0_ << 16) + __uint_as_float(w0_ & 0xFFFF0000u) \
             + __uint_as_float(w1_ << 16) + __uint_as_float(w1_ & 0xFFFF0000u); \
      uint2 wv_; wv_.x = w0_; wv_.y = w1_; \
      *(uint2*)(wb_ + (q * 8 + w) * 16) = wv_; } } }

#define KBAR() { asm volatile("s_waitcnt lgkmcnt(0)" ::: "memory"); \
  __builtin_amdgcn_s_barrier(); asm volatile("" ::: "memory"); }

  // prologue: pair 0 -> pack h0 into buf0; B(0)
  ADJ_ISS(0);
  B_ISS(BA, 0);
  PACKW(0, 0, 0);
  KBAR();
  #pragma unroll 1
  for (int pp = 0; pp < 8; ++pp){
    const int e = 2 * pp;
    // even phase e: consume BA (B(e)), buf0; pack h1 -> buf1; issue next pair last
    B_ISS(BB, e + 1);
    MFMA8(BA, 0);
    PACKW(1, 1, pp);
    if (pp < 7) ADJ_ISS(pp + 1);
    KBAR();
    // odd phase e+1: consume BB, buf1; pack h0 of new pair -> buf0
    if (pp < 7){
      B_ISS(BA, e + 2);
      MFMA8(BB, 1);
      PACKW(0, 0, pp + 1);
      KBAR();
    }
  }
  // last odd phase 15
  MFMA8(BB, 1);

#undef ADJ_ISS
#undef B_ISS
#undef MFMA8
#undef PACKW
#undef KBAR

  // ---- epilogue: per-row denominator reduce + partial store ----
  #pragma unroll
  for (int q = 0; q < 4; ++q) dred[q * 8 + w][l] = d4[q];
  __syncthreads();
  if (tid < 32){
    float s = 0.f;
    #pragma unroll
    for (int j = 0; j < 64; ++j) s += dred[tid][j];
    pd[(size_t)pb * 32 + tid] = s;
  }
  float* Pb = P + (size_t)pb * 8192 + fb + r;
  #pragma unroll
  for (int e2 = 0; e2 < 16; ++e2){
    int rr = (e2 & 3) + 8 * (e2 >> 2) + 4 * h;
    __builtin_nontemporal_store(acc[e2], Pb + (size_t)rr * 256);
  }
}

// ---------- K4: combine 4 K-split partials + softmax coeffs + sigmoid ----------
__global__ void k4_final(const float* __restrict__ P, const float* __restrict__ pd,
    const float* __restrict__ v0, const float* __restrict__ v1, float* __restrict__ out){
  const int i = blockIdx.x, n = threadIdx.x;
  const int tile = i >> 5, rloc = i & 31;
  const size_t base = (size_t)tile * 32768 + (size_t)rloc * 256 + n;
  float P0 = __builtin_nontemporal_load(P + base);
  float P1 = __builtin_nontemporal_load(P + base + 8192);
  float P2 = __builtin_nontemporal_load(P + base + 16384);
  float P3 = __builtin_nontemporal_load(P + base + 24576);
  const float* pdp = pd + (size_t)tile * 128 + rloc;
  float d0 = pdp[0], d1 = pdp[32], d2 = pdp[64], d3 = pdp[96];
  float val;
  if (i < 4096){
    float va = v0[i], vb = v1[i];
    float m = fmaxf(va, vb);
    float e0 = __expf(va - m), e1 = __expf(vb - m);
    val = (e0 * (P0 + P1) + e1 * (P2 + P3)) / (e0 * (d0 + d1) + e1 * (d2 + d3));
  } else {
    val = (P0 + P1 + P2 + P3) / (d0 + d1 + d2 + d3);
  }
  out[(size_t)i * 256 + n] = 1.0f / (1.0f + __expf(-val));
}

extern "C" void kernel_launch(void* const* d_in, const int* in_sizes, int n_in,
                              void* d_out, int out_size, void* d_ws, size_t ws_size,
                              hipStream_t stream)
{
  const float* x      = (const float*)d_in[0];
  const float* weight = (const float*)d_in[1];
  const float* av     = (const float*)d_in[2];
  const int*   adj    = (const int*)d_in[3];
  float* out = (float*)d_out;
  char* ws = (char*)d_ws;
  float* P     = (float*)(ws + 0);             // 33,554,432 B
  float* pd    = (float*)(ws + 33554432);      //    131,072 B
  u16*   outF  = (u16*)  (ws + 33685504);      //  4,194,304 B
  u16*   wT    = (u16*)  (ws + 37879808);      //    262,144 B
  u16*   pbf   = (u16*)  (ws + 38141952);      //      8,192 B
  float* v0    = (float*)(ws + 38150144);      //     16,384 B
  float* v1    = (float*)(ws + 38166528);      //     16,384 B

  k0_wt    <<<512, 256, 0, stream>>>(weight, wT);
  k1_gemm  <<<256, 512, 0, stream>>>(x, wT, av, outF, v0, v1, pbf);
  k3_main  <<<1024, 512, 0, stream>>>(adj, outF, pbf, P, pd);
  k4_final <<<8192, 256, 0, stream>>>(P, pd, v0, v1, out);
}

// Round 12
// 115.571 us; speedup vs baseline: 6.1505x; 1.0109x over previous
//
#include <hip/hip_runtime.h>

using u32 = unsigned int;
using u16 = unsigned short;

typedef __attribute__((ext_vector_type(8)))  __bf16 bf16x8;
typedef __attribute__((ext_vector_type(16))) float  f32x16;
typedef __attribute__((ext_vector_type(4)))  float  f32x4;
typedef __attribute__((ext_vector_type(4)))  int    i32x4;

__device__ __forceinline__ u32 f2bf(float f){
  u32 u = __float_as_uint(f);
  return (u + 0x7FFFu + ((u >> 16) & 1u)) >> 16;
}
__device__ __forceinline__ u32 pack2bf(float lo, float hi){
  return f2bf(lo) | (f2bf(hi) << 16);
}
__device__ __forceinline__ float bfu2f(u32 us){ return __uint_as_float(us << 16); }
__device__ __forceinline__ float lrelu(float x){ return x > 0.f ? x : 0.01f * x; }

// ---------- K0: weight [512][256] f32 -> wT [256][512] bf16 ----------
__global__ void k0_wt(const float* __restrict__ w, u16* __restrict__ wT){
  int u = blockIdx.x * 256 + threadIdx.x;
  int k = u >> 8, n = u & 255;
  wT[(size_t)n * 512 + k] = (u16)f2bf(w[(size_t)k * 256 + n]);
}

// ---------- K1: out = x@W -> outF (MFMA-frag layout) + v0/v1 + p(bf16) ----------
__global__ __launch_bounds__(512, 2) void k1_gemm(const float* __restrict__ x,
    const u16* __restrict__ wT, const float* __restrict__ av, u16* __restrict__ outF,
    float* __restrict__ v0, float* __restrict__ v1, u16* __restrict__ pbf){
  __shared__ float tb[8][32][36];
  __shared__ float afl[512];
  __shared__ float sred[2][32][17];
  __shared__ float srw[2][32];
  const int i0 = blockIdx.x * 32;
  const int tid = threadIdx.x;
  const int lane = tid & 63, wv = tid >> 6;
  const int r = lane & 31, h = lane >> 5;
  const float* xp = x + (size_t)(i0 + r) * 512 + h * 8;
  const u16*   bp = wT + (size_t)(wv * 32 + r) * 512 + h * 8;
  f32x16 acc = {};
  for (int s = 0; s < 32; ++s){
    f32x4 a0 = *(const f32x4*)xp;
    f32x4 a1 = *(const f32x4*)(xp + 4);
    i32x4 pk = { (int)pack2bf(a0[0], a0[1]), (int)pack2bf(a0[2], a0[3]),
                 (int)pack2bf(a1[0], a1[1]), (int)pack2bf(a1[2], a1[3]) };
    bf16x8 af = __builtin_bit_cast(bf16x8, pk);
    bf16x8 bf = *(const bf16x8*)bp;
    acc = __builtin_amdgcn_mfma_f32_32x32x16_bf16(af, bf, acc, 0, 0, 0);
    xp += 16; bp += 16;
  }
  #pragma unroll
  for (int re = 0; re < 16; ++re){
    int rr = (re & 3) + 8 * (re >> 2) + 4 * h;
    tb[wv][r][rr] = acc[re];
  }
  afl[tid] = av[tid];
  __syncthreads();
  {
    const int n2 = lane >> 1, ic = (lane & 1) * 16;
    const float* tp = &tb[wv][n2][ic];
    i32x4 w0 = { (int)pack2bf(tp[0],tp[1]),   (int)pack2bf(tp[2],tp[3]),
                 (int)pack2bf(tp[4],tp[5]),   (int)pack2bf(tp[6],tp[7]) };
    i32x4 w1 = { (int)pack2bf(tp[8],tp[9]),   (int)pack2bf(tp[10],tp[11]),
                 (int)pack2bf(tp[12],tp[13]), (int)pack2bf(tp[14],tp[15]) };
    const int n = wv * 32 + n2;
    const int k16 = (i0 + ic) >> 4;
    u16* op = outF + ((size_t)k16 * 256 + n) * 16;
    *(i32x4*)op = w0;
    *((i32x4*)op + 1) = w1;
  }
  const int row = tid & 31, g = tid >> 5;
  const int w8 = g >> 1, fh = (g & 1) * 16;
  float a1c = 0.f, a2c = 0.f;
  #pragma unroll
  for (int f = 0; f < 16; ++f){
    float tv = tb[w8][fh + f][row];
    a1c = fmaf(tv, afl[w8 * 32 + fh + f], a1c);
    a2c = fmaf(tv, afl[256 + w8 * 32 + fh + f], a2c);
  }
  sred[0][row][g] = a1c; sred[1][row][g] = a2c;
  __syncthreads();
  if (tid < 64){
    int which = tid >> 5, r2 = tid & 31;
    float s = 0.f;
    #pragma unroll
    for (int g2 = 0; g2 < 16; ++g2) s += sred[which][r2][g2];
    srw[which][r2] = s;
  }
  __syncthreads();
  if (tid < 16){
    int k = (i0 >> 1) + tid;
    float sa  = srw[0][2*tid],   sb  = srw[1][2*tid];
    float sa1 = srw[0][2*tid+1], sb1 = srw[1][2*tid+1];
    v0[k] = lrelu(sa + sb);
    v1[k] = lrelu(sa1 + sb1);
    float w = lrelu(sa + sb1);
    pbf[k] = (u16)f2bf(__expf(w));
  }
}

// ---------- K3: binary GEMM, 2KB-run adj streaming, 512-K phases, 1 round ----------
// grid 512 (2/CU, exactly 1 round): xcd=bid&7 -> chunk c=xcd&1, tile=(xcd>>1)*64+slot.
// Block: 32 rows x 256 feats x K-chunk 4096 = 8 phases of 512 K. 8 waves x 32 feats.
// Per phase per wave: 8 adj loads = 4 rows x 2KB CONTIGUOUS; 32 B-frag loads consumed
// at 4-frag sub-step ping-pong; 32 MFMA; pack at phase end (slack ~7 sub-steps).
// A staged in LDS, slice stride 528 u16 (pad 16B/slice): read & write at bank floor.
__global__ __launch_bounds__(512, 2) void k3_main(const int* __restrict__ adj,
    const u16* __restrict__ outF, const u16* __restrict__ pbf,
    float* __restrict__ P, float* __restrict__ pd){
  __shared__ u16 AbS[2][16896];   // 2 x 32 slices x 528 u16 (1056B padded) = 67,584 B
  __shared__ u32 plS[2048];       // p bf16-pairs, full 4096-period = 8,192 B
  __shared__ float dshS[32];
  const int bid = blockIdx.x;
  const int xcd = bid & 7, slot = bid >> 3;      // slot 0..63
  const int c = xcd & 1;
  const int tile = (xcd >> 1) * 64 + slot;       // 0..255 ; <128 top
  const bool top = tile < 128;
  const int i0 = tile * 32;
  const int pb = tile * 2 + c;
  const int tid = threadIdx.x, l = tid & 63, w = tid >> 6;
  const int r = l & 31, h = l >> 5;
  const int fb = w * 32;
  const int* aq0 = adj + (size_t)(i0 + w) * 8192 + c * 4096 + l * 4;
  const u16* bq0 = outF + (size_t)c * 1048576 + (fb + r) * 16 + h * 8;

  // stage p-pairs (full period; top = 1.0)
  if (top){
    plS[tid] = 0x3F803F80u; plS[tid + 512] = 0x3F803F80u;
    plS[tid + 1024] = 0x3F803F80u; plS[tid + 1536] = 0x3F803F80u;
  } else {
    const u32* ps = (const u32*)pbf;
    plS[tid] = ps[tid]; plS[tid + 512] = ps[tid + 512];
    plS[tid + 1024] = ps[tid + 1024]; plS[tid + 1536] = ps[tid + 1536];
  }
  __syncthreads();

  i32x4 ar[8];                      // [row q(4)][half L(2)]
  bf16x8 BA[4], BB[4];
  f32x16 acc = {};
  float d4[4] = {0.f, 0.f, 0.f, 0.f};

  // adj: ar[q*2+L] = row (q*8+w), 1KB half L of phase PH's 2KB run
#define ADJ_H(HF_,PH_) { \
  _Pragma("unroll") for (int j_ = 0; j_ < 2; ++j_){ \
    const int q_ = (HF_) * 2 + j_; \
    const int* ap_ = aq0 + q_ * 65536 + (PH_) * 512; \
    ar[q_*2]   = *(const i32x4*)ap_; \
    ar[q_*2+1] = *(const i32x4*)(ap_ + 256); } \
  asm volatile("" ::: "memory"); }

#define B_ISS4(B_,G_) { const u16* bb_ = bq0 + (size_t)(G_) * 4096; \
  B_[0] = *(const bf16x8*)bb_;            B_[1] = *(const bf16x8*)(bb_ + 4096); \
  B_[2] = *(const bf16x8*)(bb_ + 8192);   B_[3] = *(const bf16x8*)(bb_ + 12288); \
  asm volatile("" ::: "memory"); }

#define MFMA4(B_,RB_,S_) { \
  __builtin_amdgcn_s_setprio(1); \
  _Pragma("unroll") for (int j_ = 0; j_ < 4; ++j_){ \
    bf16x8 a_ = *(const bf16x8*)((RB_) + ((S_) * 4 + j_) * 528 + r * 16 + h * 8); \
    acc = __builtin_amdgcn_mfma_f32_32x32x16_bf16(a_, B_[j_], acc, 0, 0, 0); } \
  __builtin_amdgcn_s_setprio(0); }

  // pack phase PH_ into buffer WB_ (u16*), consume ar, accumulate d4
#define PACK(PH_,WB_) { \
  _Pragma("unroll") for (int q_ = 0; q_ < 4; ++q_){ \
    const int row_ = q_ * 8 + w; \
    _Pragma("unroll") for (int L_ = 0; L_ < 2; ++L_){ \
      i32x4 a_ = ar[q_*2 + L_]; \
      uint2 pp_ = *(const uint2*)(plS + (((PH_) & 7) * 256 + L_ * 128 + 2 * l)); \
      u32 w0_ = ((((u32)(-a_[0])) & 0xFFFFu) | (((u32)(-a_[1])) << 16)) & pp_.x; \
      u32 w1_ = ((((u32)(-a_[2])) & 0xFFFFu) | (((u32)(-a_[3])) << 16)) & pp_.y; \
      d4[q_] += __uint_as_float(w0_ << 16) + __uint_as_float(w0_ & 0xFFFF0000u) \
              + __uint_as_float(w1_ << 16) + __uint_as_float(w1_ & 0xFFFF0000u); \
      const int slot_ = L_ * 16 + (l >> 2); \
      uint2 wv_; wv_.x = w0_; wv_.y = w1_; \
      *(uint2*)((WB_) + slot_ * 528 + row_ * 16 + (l & 3) * 4) = wv_; } } }

#define KBAR() { asm volatile("s_waitcnt lgkmcnt(0)" ::: "memory"); \
  __builtin_amdgcn_s_barrier(); asm volatile("" ::: "memory"); }

  // prologue: adj(ph0), B(slices 0..3), pack ph0 -> buf0
  ADJ_H(0, 0); ADJ_H(1, 0);
  B_ISS4(BA, 0);
  PACK(0, &AbS[0][0]);
  KBAR();

  #pragma unroll 1
  for (int t = 0; t < 8; ++t){
    const u16* rb = &AbS[t & 1][0];
    u16* wb = &AbS[(t + 1) & 1][0];
    #pragma unroll
    for (int s = 0; s < 8; ++s){
      if (!(t == 7 && s == 7)){
        const int g = t * 32 + (s + 1) * 4;
        if (s & 1){ B_ISS4(BA, g); } else { B_ISS4(BB, g); }
      }
      if (t < 7 && s == 0) ADJ_H(0, t + 1);
      if (t < 7 && s == 1) ADJ_H(1, t + 1);
      if (s & 1){ MFMA4(BB, rb, s); } else { MFMA4(BA, rb, s); }
    }
    if (t < 7){
      PACK(t + 1, wb);
      KBAR();
    }
  }

#undef ADJ_H
#undef B_ISS4
#undef MFMA4
#undef PACK
#undef KBAR

  // ---- epilogue: wave-reduce denominators + partial store ----
  #pragma unroll
  for (int q = 0; q < 4; ++q){
    float v = d4[q];
    #pragma unroll
    for (int mk = 1; mk < 64; mk <<= 1) v += __shfl_xor(v, mk);
    if (l == 0) dshS[q * 8 + w] = v;
  }
  __syncthreads();
  if (tid < 32) pd[(size_t)pb * 32 + tid] = dshS[tid];
  float* Pb = P + (size_t)pb * 8192 + fb + r;
  #pragma unroll
  for (int e = 0; e < 16; ++e){
    int rr = (e & 3) + 8 * (e >> 2) + 4 * h;
    __builtin_nontemporal_store(acc[e], Pb + (size_t)rr * 256);
  }
}

// ---------- K4: combine K-split partials + softmax coeffs + sigmoid ----------
__global__ void k4_final(const float* __restrict__ P, const float* __restrict__ pd,
    const float* __restrict__ v0, const float* __restrict__ v1, float* __restrict__ out){
  const int i = blockIdx.x, n = threadIdx.x;
  const int tile = i >> 5, rloc = i & 31;
  const size_t base = (size_t)tile * 16384 + (size_t)rloc * 256 + n;
  float P0 = __builtin_nontemporal_load(P + base);
  float P1 = __builtin_nontemporal_load(P + base + 8192);
  float d0 = pd[tile * 64 + rloc];
  float d1 = pd[tile * 64 + 32 + rloc];
  float val;
  if (i < 4096){
    float va = v0[i], vb = v1[i];
    float m = fmaxf(va, vb);
    float e0 = __expf(va - m), e1 = __expf(vb - m);
    val = (e0 * P0 + e1 * P1) / (e0 * d0 + e1 * d1);
  } else {
    val = (P0 + P1) / (d0 + d1);
  }
  out[(size_t)i * 256 + n] = 1.0f / (1.0f + __expf(-val));
}

extern "C" void kernel_launch(void* const* d_in, const int* in_sizes, int n_in,
                              void* d_out, int out_size, void* d_ws, size_t ws_size,
                              hipStream_t stream)
{
  const float* x      = (const float*)d_in[0];
  const float* weight = (const float*)d_in[1];
  const float* av     = (const float*)d_in[2];
  const int*   adj    = (const int*)d_in[3];
  float* out = (float*)d_out;
  char* ws = (char*)d_ws;
  float* P     = (float*)(ws + 0);             // 16,777,216 B
  float* pd    = (float*)(ws + 16777216);      //     65,536 B
  u16*   outF  = (u16*)  (ws + 16842752);      //  4,194,304 B
  u16*   wT    = (u16*)  (ws + 21037056);      //    262,144 B
  u16*   pbf   = (u16*)  (ws + 21299200);      //      8,192 B
  float* v0    = (float*)(ws + 21307392);      //     16,384 B
  float* v1    = (float*)(ws + 21323776);      //     16,384 B

  k0_wt    <<<512, 256, 0, stream>>>(weight, wT);
  k1_gemm  <<<256, 512, 0, stream>>>(x, wT, av, outF, v0, v1, pbf);
  k3_main  <<<512, 512, 0, stream>>>(adj, outF, pbf, P, pd);
  k4_final <<<8192, 256, 0, stream>>>(P, pd, v0, v1, out);
}

// Round 13
// 111.244 us; speedup vs baseline: 6.3898x; 1.0389x over previous
//
#include <hip/hip_runtime.h>

using u32 = unsigned int;
using u16 = unsigned short;

typedef __attribute__((ext_vector_type(8)))  __bf16 bf16x8;
typedef __attribute__((ext_vector_type(16))) float  f32x16;
typedef __attribute__((ext_vector_type(4)))  float  f32x4;
typedef __attribute__((ext_vector_type(4)))  int    i32x4;

__device__ __forceinline__ u32 f2bf(float f){
  u32 u = __float_as_uint(f);
  return (u + 0x7FFFu + ((u >> 16) & 1u)) >> 16;
}
__device__ __forceinline__ u32 pack2bf(float lo, float hi){
  return f2bf(lo) | (f2bf(hi) << 16);
}
__device__ __forceinline__ float bfu2f(u32 us){ return __uint_as_float(us << 16); }
__device__ __forceinline__ float lrelu(float x){ return x > 0.f ? x : 0.01f * x; }

// ---------- K0: weight [512][256] f32 -> wT [256][512] bf16 ----------
__global__ void k0_wt(const float* __restrict__ w, u16* __restrict__ wT){
  int u = blockIdx.x * 256 + threadIdx.x;
  int k = u >> 8, n = u & 255;
  wT[(size_t)n * 512 + k] = (u16)f2bf(w[(size_t)k * 256 + n]);
}

// ---------- K1: out = x@W -> outF (MFMA-frag layout) + v0/v1 + p(bf16) ----------
__global__ __launch_bounds__(512, 2) void k1_gemm(const float* __restrict__ x,
    const u16* __restrict__ wT, const float* __restrict__ av, u16* __restrict__ outF,
    float* __restrict__ v0, float* __restrict__ v1, u16* __restrict__ pbf){
  __shared__ float tb[8][32][36];
  __shared__ float afl[512];
  __shared__ float sred[2][32][17];
  __shared__ float srw[2][32];
  const int i0 = blockIdx.x * 32;
  const int tid = threadIdx.x;
  const int lane = tid & 63, wv = tid >> 6;
  const int r = lane & 31, h = lane >> 5;
  const float* xp = x + (size_t)(i0 + r) * 512 + h * 8;
  const u16*   bp = wT + (size_t)(wv * 32 + r) * 512 + h * 8;
  f32x16 acc = {};
  for (int s = 0; s < 32; ++s){
    f32x4 a0 = *(const f32x4*)xp;
    f32x4 a1 = *(const f32x4*)(xp + 4);
    i32x4 pk = { (int)pack2bf(a0[0], a0[1]), (int)pack2bf(a0[2], a0[3]),
                 (int)pack2bf(a1[0], a1[1]), (int)pack2bf(a1[2], a1[3]) };
    bf16x8 af = __builtin_bit_cast(bf16x8, pk);
    bf16x8 bf = *(const bf16x8*)bp;
    acc = __builtin_amdgcn_mfma_f32_32x32x16_bf16(af, bf, acc, 0, 0, 0);
    xp += 16; bp += 16;
  }
  #pragma unroll
  for (int re = 0; re < 16; ++re){
    int rr = (re & 3) + 8 * (re >> 2) + 4 * h;
    tb[wv][r][rr] = acc[re];
  }
  afl[tid] = av[tid];
  __syncthreads();
  {
    const int n2 = lane >> 1, ic = (lane & 1) * 16;
    const float* tp = &tb[wv][n2][ic];
    i32x4 w0 = { (int)pack2bf(tp[0],tp[1]),   (int)pack2bf(tp[2],tp[3]),
                 (int)pack2bf(tp[4],tp[5]),   (int)pack2bf(tp[6],tp[7]) };
    i32x4 w1 = { (int)pack2bf(tp[8],tp[9]),   (int)pack2bf(tp[10],tp[11]),
                 (int)pack2bf(tp[12],tp[13]), (int)pack2bf(tp[14],tp[15]) };
    const int n = wv * 32 + n2;
    const int k16 = (i0 + ic) >> 4;
    u16* op = outF + ((size_t)k16 * 256 + n) * 16;
    *(i32x4*)op = w0;
    *((i32x4*)op + 1) = w1;
  }
  const int row = tid & 31, g = tid >> 5;
  const int w8 = g >> 1, fh = (g & 1) * 16;
  float a1c = 0.f, a2c = 0.f;
  #pragma unroll
  for (int f = 0; f < 16; ++f){
    float tv = tb[w8][fh + f][row];
    a1c = fmaf(tv, afl[w8 * 32 + fh + f], a1c);
    a2c = fmaf(tv, afl[256 + w8 * 32 + fh + f], a2c);
  }
  sred[0][row][g] = a1c; sred[1][row][g] = a2c;
  __syncthreads();
  if (tid < 64){
    int which = tid >> 5, r2 = tid & 31;
    float s = 0.f;
    #pragma unroll
    for (int g2 = 0; g2 < 16; ++g2) s += sred[which][r2][g2];
    srw[which][r2] = s;
  }
  __syncthreads();
  if (tid < 16){
    int k = (i0 >> 1) + tid;
    float sa  = srw[0][2*tid],   sb  = srw[1][2*tid];
    float sa1 = srw[0][2*tid+1], sb1 = srw[1][2*tid+1];
    v0[k] = lrelu(sa + sb);
    v1[k] = lrelu(sa1 + sb1);
    float w = lrelu(sa + sb1);
    pbf[k] = (u16)f2bf(__expf(w));
  }
}

// ---------- K3: binary GEMM, 64-row tiles (B-L2 traffic halved), split-K=4 ----------
// grid 512 (2/CU): xcd=bid&7 -> half=xcd&1 (top/bottom), chunk c=xcd>>1; slot=bid>>3.
// Block: 64 rows x 256 feats x K-chunk 2048 = 8 phases of 256 K. 8 waves x 32 feats,
// each wave computes TWO 32-row blocks per B-frag (acc = 2 f32x16).
// Phase = 4 sub-steps of 4 k16-slices: {B_ISS4(next set), MFMA4 both row-blocks}.
// adj: 4+4 rows/wave, 1KB contiguous per row, issued subs 0/1, packed at phase end.
// LDS A: [16 slices][2 halves][64 rows][8 bf16], slice stride 1048 u16 (pad 24).
__global__ __launch_bounds__(512, 2) void k3_main(const int* __restrict__ adj,
    const u16* __restrict__ outF, const u16* __restrict__ pbf,
    float* __restrict__ P, float* __restrict__ pd){
  __shared__ u16 AbS[2][16768];   // 2 x 16 x 1048 u16 = 67,072 B
  __shared__ u32 plS[1024];       // this chunk's 2048 p values as bf16-pairs
  __shared__ float dshS[64];
  const int bid = blockIdx.x;
  const int xcd = bid & 7, slot = bid >> 3;
  const int half = xcd & 1, c = xcd >> 1;
  const int tile = half * 64 + slot;       // 0..127 ; <64 top
  const bool top = half == 0;
  const int i0 = tile * 64;
  const int kbase = c * 2048;
  const int pb = tile * 4 + c;
  const int tid = threadIdx.x, l = tid & 63, w = tid >> 6;
  const int r = l & 31, h = l >> 5, fb = w * 32;
  const int* aq0 = adj + (size_t)(i0 + w) * 8192 + kbase + l * 4;
  const u16* bq0 = outF + (size_t)c * 524288 + (fb + r) * 16 + h * 8;
  const int sl_ = l >> 2, hp_ = (l >> 1) & 1, off_ = 4 * (l & 1);
  u16* const wp0 = &AbS[0][0] + sl_ * 1048 + hp_ * 512 + off_;
  const u16* const rp0 = &AbS[0][0] + h * 512 + r * 8;

  // stage p (chunk covers K [kbase,kbase+2048); p period 4096 -> half (c&1))
  if (top){
    plS[tid] = 0x3F803F80u; plS[tid + 512] = 0x3F803F80u;
  } else {
    const u32* ps = (const u32*)pbf + (c & 1) * 1024;
    plS[tid] = ps[tid]; plS[tid + 512] = ps[tid + 512];
  }
  __syncthreads();

  i32x4 arA[4], arB[4];
  bf16x8 BA[4], BB[4];
  f32x16 acc0 = {}, acc1 = {};
  float dA[4] = {0.f,0.f,0.f,0.f}, dB[4] = {0.f,0.f,0.f,0.f};

#define ADJ_SET(AR_,Q0_,T_) { \
  _Pragma("unroll") for (int q_ = 0; q_ < 4; ++q_) \
    AR_[q_] = *(const i32x4*)(aq0 + (size_t)((Q0_) + q_) * 65536 + (T_) * 256); \
  asm volatile("" ::: "memory"); }

#define B_ISS4(B_,G_) { const u16* bb_ = bq0 + (size_t)(G_) * 4096; \
  B_[0] = *(const bf16x8*)bb_;          B_[1] = *(const bf16x8*)(bb_ + 4096); \
  B_[2] = *(const bf16x8*)(bb_ + 8192); B_[3] = *(const bf16x8*)(bb_ + 12288); \
  asm volatile("" ::: "memory"); }

#define MFMA4(B_,BUF_,S0_) { \
  const u16* rb_ = rp0 + (BUF_) * 16768 + (S0_) * 1048; \
  __builtin_amdgcn_s_setprio(1); \
  _Pragma("unroll") for (int j_ = 0; j_ < 4; ++j_){ \
    bf16x8 a0_ = *(const bf16x8*)(rb_ + j_ * 1048); \
    bf16x8 a1_ = *(const bf16x8*)(rb_ + j_ * 1048 + 256); \
    acc0 = __builtin_amdgcn_mfma_f32_32x32x16_bf16(a0_, B_[j_], acc0, 0, 0, 0); \
    acc1 = __builtin_amdgcn_mfma_f32_32x32x16_bf16(a1_, B_[j_], acc1, 0, 0, 0); } \
  __builtin_amdgcn_s_setprio(0); }

#define PACK_SET(AR_,D_,RB_,T_,BUF_) { \
  _Pragma("unroll") for (int q_ = 0; q_ < 4; ++q_){ \
    const int row_ = (RB_) * 32 + q_ * 8 + w; \
    i32x4 a_ = AR_[q_]; \
    u32 p0_ = plS[((T_) & 7) * 128 + 2 * l]; \
    u32 p1_ = plS[((T_) & 7) * 128 + 2 * l + 1]; \
    u32 w0_ = ((((u32)(-a_[0])) & 0xFFFFu) | (((u32)(-a_[1])) << 16)) & p0_; \
    u32 w1_ = ((((u32)(-a_[2])) & 0xFFFFu) | (((u32)(-a_[3])) << 16)) & p1_; \
    D_[q_] += __uint_as_float(w0_ << 16) + __uint_as_float(w0_ & 0xFFFF0000u) \
            + __uint_as_float(w1_ << 16) + __uint_as_float(w1_ & 0xFFFF0000u); \
    uint2 wv_; wv_.x = w0_; wv_.y = w1_; \
    *(uint2*)(wp0 + (BUF_) * 16768 + row_ * 8) = wv_; } }

#define KBAR() { asm volatile("s_waitcnt lgkmcnt(0)" ::: "memory"); \
  __builtin_amdgcn_s_barrier(); asm volatile("" ::: "memory"); }

  // prologue: pack phase 0 into buf 0; BA <- slices 0..3
  ADJ_SET(arA, 0, 0);
  ADJ_SET(arB, 4, 0);
  B_ISS4(BA, 0);
  PACK_SET(arA, dA, 0, 0, 0);
  PACK_SET(arB, dB, 1, 0, 0);
  KBAR();

  #pragma unroll 1
  for (int t = 0; t < 8; ++t){
    const int buf = t & 1;
    const int g0 = t * 16;
    // sub0
    B_ISS4(BB, g0 + 4);
    if (t < 7) ADJ_SET(arA, 0, t + 1);
    MFMA4(BA, buf, 0);
    // sub1
    B_ISS4(BA, g0 + 8);
    if (t < 7) ADJ_SET(arB, 4, t + 1);
    MFMA4(BB, buf, 4);
    // sub2
    B_ISS4(BB, g0 + 12);
    MFMA4(BA, buf, 8);
    // sub3
    if (t < 7){ B_ISS4(BA, g0 + 16); }
    MFMA4(BB, buf, 12);
    if (t < 7){
      PACK_SET(arA, dA, 0, t + 1, buf ^ 1);
      PACK_SET(arB, dB, 1, t + 1, buf ^ 1);
      KBAR();
    }
  }

#undef ADJ_SET
#undef B_ISS4
#undef MFMA4
#undef PACK_SET
#undef KBAR

  // ---- epilogue: per-row denominator reduce + partial store ----
  #pragma unroll
  for (int q = 0; q < 4; ++q){
    float vA = dA[q], vB = dB[q];
    #pragma unroll
    for (int mk = 1; mk < 64; mk <<= 1){
      vA += __shfl_xor(vA, mk);
      vB += __shfl_xor(vB, mk);
    }
    if (l == 0){ dshS[q * 8 + w] = vA; dshS[32 + q * 8 + w] = vB; }
  }
  __syncthreads();
  if (tid < 64) pd[(size_t)pb * 64 + tid] = dshS[tid];
  float* Pb = P + (size_t)pb * 16384 + fb + r;
  #pragma unroll
  for (int e = 0; e < 16; ++e){
    int rr = (e & 3) + 8 * (e >> 2) + 4 * h;
    __builtin_nontemporal_store(acc0[e], Pb + (size_t)rr * 256);
    __builtin_nontemporal_store(acc1[e], Pb + (size_t)(rr + 32) * 256);
  }
}

// ---------- K4: combine 4 K-split partials + softmax coeffs + sigmoid ----------
__global__ void k4_final(const float* __restrict__ P, const float* __restrict__ pd,
    const float* __restrict__ v0, const float* __restrict__ v1, float* __restrict__ out){
  const int i = blockIdx.x, n = threadIdx.x;
  const int tile = i >> 6, rloc = i & 63;
  const size_t base = ((size_t)tile * 4 * 64 + rloc) * 256 + n;
  float P0 = __builtin_nontemporal_load(P + base);
  float P1 = __builtin_nontemporal_load(P + base + 16384);
  float P2 = __builtin_nontemporal_load(P + base + 32768);
  float P3 = __builtin_nontemporal_load(P + base + 49152);
  const float* pdp = pd + (size_t)tile * 256 + rloc;
  float d0 = pdp[0], d1 = pdp[64], d2 = pdp[128], d3 = pdp[192];
  float val;
  if (i < 4096){
    float va = v0[i], vb = v1[i];
    float m = fmaxf(va, vb);
    float e0 = __expf(va - m), e1 = __expf(vb - m);
    val = (e0 * (P0 + P1 + P2 + P3) * 0.f + e0 * (P0 + P1 + P2 + P3)) /
          (1.f); // placeholder avoided; real formula below
    // top rows: chunks 0,1 cover K<4096 (coef e0), chunks 2,3 cover K>=4096 (coef e1)
    val = (e0 * (P0 + P1) + e1 * (P2 + P3)) / (e0 * (d0 + d1) + e1 * (d2 + d3));
  } else {
    val = (P0 + P1 + P2 + P3) / (d0 + d1 + d2 + d3);
  }
  out[(size_t)i * 256 + n] = 1.0f / (1.0f + __expf(-val));
}

extern "C" void kernel_launch(void* const* d_in, const int* in_sizes, int n_in,
                              void* d_out, int out_size, void* d_ws, size_t ws_size,
                              hipStream_t stream)
{
  const float* x      = (const float*)d_in[0];
  const float* weight = (const float*)d_in[1];
  const float* av     = (const float*)d_in[2];
  const int*   adj    = (const int*)d_in[3];
  float* out = (float*)d_out;
  char* ws = (char*)d_ws;
  float* P     = (float*)(ws + 0);             // 33,554,432 B
  float* pd    = (float*)(ws + 33554432);      //    131,072 B
  u16*   outF  = (u16*)  (ws + 33685504);      //  4,194,304 B
  u16*   wT    = (u16*)  (ws + 37879808);      //    262,144 B
  u16*   pbf   = (u16*)  (ws + 38141952);      //      8,192 B
  float* v0    = (float*)(ws + 38150144);      //     16,384 B
  float* v1    = (float*)(ws + 38166528);      //     16,384 B

  k0_wt    <<<512, 256, 0, stream>>>(weight, wT);
  k1_gemm  <<<256, 512, 0, stream>>>(x, wT, av, outF, v0, v1, pbf);
  k3_main  <<<512, 512, 0, stream>>>(adj, outF, pbf, P, pd);
  k4_final <<<8192, 256, 0, stream>>>(P, pd, v0, v1, out);
}